// Round 5
// baseline (283.502 us; speedup 1.0000x reference)
//
#include <hip/hip_runtime.h>
#include <cfloat>
#include <stdint.h>

// MultiDepthLimitedMSELoss: per-row greedy matching + masked MSE -> scalar.
// R5: force MLP+ILP. R4 post-mortem: VGPR=36 proved the compiler sank the
// 4 rows' loads back into a serial per-row loop (one latency exposure per
// ~600-cy dependent argmin chain). Fixes:
//  - unconditional clamped loads + sched_barrier(0): all 8 dwordx4 issued
//    before any compute, cannot be sunk
//  - i-outer / k-inner full unroll: 4 independent knockout chains in flight
//  - packed-uint argmin: dp = (|diff|&~7)|j, depth-3 umin tree (v_min3_u32),
//    knockout by dp==best (index embedded -> exactly one winner, no tie
//    blowup), loss term from masked bits (<=2^-21 rel perturbation, harmless
//    vs 2.4e-2 threshold)

#define DVALS 8
#define RPT 4

__device__ __forceinline__ uint32_t umin2(uint32_t a, uint32_t b) {
    return a < b ? a : b;
}

__global__ __launch_bounds__(256, 4) void mdmse_match_kernel(
    const float* __restrict__ outputs,
    const float* __restrict__ targets,
    float* __restrict__ out,
    int n_rows,
    float inv_count)
{
    const int tid = blockIdx.x * blockDim.x + threadIdx.x;
    const int stride = gridDim.x * blockDim.x;

    float local = 0.0f;

    for (int base = tid; base < n_rows; base += stride * RPT) {
        float cpy[RPT][DVALS];
        float t[RPT][DVALS];
        float w[RPT];

        // ---- load phase: 8x global_load_dwordx4, unconditional (clamped) ----
#pragma unroll
        for (int k = 0; k < RPT; ++k) {
            int r = base + k * stride;
            w[k] = (r < n_rows) ? 1.0f : 0.0f;     // OOB rows contribute 0
            int rc = (r < n_rows) ? r : (n_rows - 1);
            const float4* op = reinterpret_cast<const float4*>(outputs + (size_t)rc * DVALS);
            const float4* tp = reinterpret_cast<const float4*>(targets + (size_t)rc * DVALS);
            float4 o0 = op[0], o1 = op[1];
            float4 t0 = tp[0], t1 = tp[1];
            cpy[k][0]=o0.x; cpy[k][1]=o0.y; cpy[k][2]=o0.z; cpy[k][3]=o0.w;
            cpy[k][4]=o1.x; cpy[k][5]=o1.y; cpy[k][6]=o1.z; cpy[k][7]=o1.w;
            t[k][0]=t0.x; t[k][1]=t0.y; t[k][2]=t0.z; t[k][3]=t0.w;
            t[k][4]=t1.x; t[k][5]=t1.y; t[k][6]=t1.z; t[k][7]=t1.w;
        }
        // keep all loads issued above this point (don't let them sink)
        __builtin_amdgcn_sched_barrier(0);

        // ---- match phase: 4 independent chains interleaved (ILP=4) ----
        float rs[RPT] = {0.0f, 0.0f, 0.0f, 0.0f};
#pragma unroll
        for (int i = 0; i < DVALS; ++i) {
#pragma unroll
            for (int k = 0; k < RPT; ++k) {
                float tc = t[k][i];
                uint32_t dp[DVALS];
#pragma unroll
                for (int j = 0; j < DVALS; ++j) {
                    float diff = cpy[k][j] - tc;
                    // abs + clear low-3 mantissa bits + embed index: 1 VOP3
                    dp[j] = (__float_as_uint(diff) & 0x7FFFFFF8u) | (uint32_t)j;
                }
                // depth-3 unsigned min tree (monotone for non-neg IEEE bits);
                // low-index wins ties automatically (index in low bits)
                uint32_t best = umin2(umin2(umin2(dp[0], dp[1]), umin2(dp[2], dp[3])),
                                      umin2(umin2(dp[4], dp[5]), umin2(dp[6], dp[7])));
                // knockout: exactly one j matches (index embedded)
#pragma unroll
                for (int j = 0; j < DVALS; ++j)
                    cpy[k][j] = (dp[j] == best) ? FLT_MAX : cpy[k][j];
                // |bestv - tc| up to cleared low bits; t==0 -> term vanishes
                float bd = __uint_as_float(best & 0xFFFFFFF8u);
                float c = (tc != 0.0f) ? bd : 0.0f;
                rs[k] = fmaf(c, c, rs[k]);
            }
        }
#pragma unroll
        for (int k = 0; k < RPT; ++k)
            local = fmaf(w[k], rs[k], local);
    }

    // wave-64 butterfly reduce
#pragma unroll
    for (int off = 32; off > 0; off >>= 1)
        local += __shfl_down(local, off, 64);

    __shared__ float wsum[4];  // 256 threads / 64 lanes
    int lane = threadIdx.x & 63;
    int wid  = threadIdx.x >> 6;
    if (lane == 0) wsum[wid] = local;
    __syncthreads();

    if (threadIdx.x == 0) {
        float s = wsum[0] + wsum[1] + wsum[2] + wsum[3];
        atomicAdd(out, s * inv_count);  // ~4096 atomics, negligible contention
    }
}

extern "C" void kernel_launch(void* const* d_in, const int* in_sizes, int n_in,
                              void* d_out, int out_size, void* d_ws, size_t ws_size,
                              hipStream_t stream)
{
    const float* outputs = (const float*)d_in[0];
    const float* targets = (const float*)d_in[1];
    float* out = (float*)d_out;

    const int n_rows = in_sizes[0] / DVALS;

    // d_out is re-poisoned 0xAA before every timed launch -> zero it ourselves.
    hipMemsetAsync(out, 0, sizeof(float), stream);

    const int block = 256;
    long long want = ((long long)n_rows + (long long)block * RPT - 1) /
                     ((long long)block * RPT);
    int grid = (int)want;            // N=4.19M -> 4096 blocks, one outer iter
    if (grid < 1) grid = 1;

    const float inv_count = 1.0f / ((float)n_rows * (float)DVALS);
    mdmse_match_kernel<<<grid, block, 0, stream>>>(outputs, targets, out,
                                                   n_rows, inv_count);
}